// Round 4
// baseline (229.557 us; speedup 1.0000x reference)
//
#include <hip/hip_runtime.h>
#include <cstdint>
#include <cstddef>

#define DEV __device__ __forceinline__

typedef float f2 __attribute__((ext_vector_type(2)));

constexpr float L2E = 1.4426950408889634f;   // log2(e)
constexpr float T2E = 2.8853900817779268f;   // 2*log2(e)

DEV float readlanef(float v, int l) {
    return __uint_as_float(__builtin_amdgcn_readlane(__float_as_uint(v), l));
}
// sigmoid(x) with pre-scaled argument y = L2E*x : 1/(1+2^-y)
DEV float fsig2(float y)  { return __builtin_amdgcn_rcpf(1.0f + __builtin_amdgcn_exp2f(-y)); }
// tanh(x) with pre-scaled argument y = 2*L2E*x : 1 - 2/(1+2^y)
DEV float ftanh2(float y) { return 1.0f - 2.0f * __builtin_amdgcn_rcpf(1.0f + __builtin_amdgcn_exp2f(y)); }

// DPP row rotate-right by N within each 16-lane row: dst[i] = src[(i-N)&15 of row]
template<int N> DEV float rorf(float v) {
    return __uint_as_float((unsigned)__builtin_amdgcn_mov_dpp(
        (int)__float_as_uint(v), 0x120 + N, 0xF, 0xF, false));
}
// ds_swizzle xor-16: dst[i] = src[i^16] (within each 32-lane half)
DEV float swzx16(float v) {
    return __uint_as_float((unsigned)__builtin_amdgcn_ds_swizzle(
        (int)__float_as_uint(v), 0x401F));
}

// ---------------- ws layout (float offsets) ----------------
constexpr size_t ACC   = 0;                 // 64  (2 tracks x (16 sum + 16 sumsq))
constexpr size_t LO    = 128;               // 65536  Lo[64][128][8]
constexpr size_t RO    = LO + 65536;        // 65536  Ro[64][128][8]
constexpr size_t HBUF  = RO + 65536;        // 262144 h[track][8192][16]
constexpr size_t ZLAST = HBUF + 262144;     // 1024   zlast[64][16]
constexpr size_t XW    = ZLAST + 1024;      // 393216 xw[64][128][48] (pre-scaled)
constexpr size_t WS_NEED = XW + 393216;     // floats

// ===== K1: gate GRU, 1 seq/wave, skewed layers, DPP broadcast =====
// rows of 16 lanes: row0/2 = layer0, row1/3 = layer1; h replicated across
// both 8-lane halves of a row (lane m holds h_{m&7}).
__global__ __launch_bounds__(64, 1) void k1_gate(
    const float* __restrict__ Local, const float* __restrict__ Remote,
    const float* __restrict__ Wih0, const float* __restrict__ Whh0,
    const float* __restrict__ bih0, const float* __restrict__ bhh0,
    const float* __restrict__ Wih1, const float* __restrict__ Whh1,
    const float* __restrict__ bih1, const float* __restrict__ bhh1,
    float* __restrict__ ws)
{
    const int tid = threadIdx.x;
    const int j = tid & 7;
    const int layer = (tid >> 4) & 1;
    const int blk = blockIdx.x;
    const int track = blk >> 6;
    const int b = blk & 63;
    if (blk == 0) ws[ACC + tid] = 0.f;

    __shared__ float xwg[128][24];     // pre-scaled bih0 + Wih0 . x(t)
    __shared__ float h1all[128][9];

    const float* __restrict__ src = track ? Remote : Local;
    for (int t = tid; t < 128; t += 64) {
        const float* p = src + ((size_t)b * 128 + t) * 132 + 128;
        float x0 = p[0], x1 = p[1], x2 = p[2];
#pragma unroll
        for (int u = 0; u < 24; ++u) {
            float a = bih0[u];
            a = fmaf(Wih0[u * 3 + 0], x0, a);
            a = fmaf(Wih0[u * 3 + 1], x1, a);
            a = fmaf(Wih0[u * 3 + 2], x2, a);
            xwg[t][u] = a * (u < 16 ? L2E : T2E);
        }
    }

    // A = own-layer h (Whh of own layer); B = other-layer h (Wih1, layer1 only)
    const float* __restrict__ WA = layer ? Whh1 : Whh0;
    const float mhi = layer ? 1.f : 0.f;
    const float m0f = layer ? 0.f : 1.f;
    f2 wa2r[4], wa2z[4], wa2c[4], wb2r[4], wb2z[4], wb2c[4];
#pragma unroll
    for (int m = 0; m < 4; ++m) {
        int k0 = (j - 2 * m) & 7, k1i = (j - 2 * m - 1) & 7;
        wa2r[m].x = L2E * WA[j * 8 + k0];        wa2r[m].y = L2E * WA[j * 8 + k1i];
        wa2z[m].x = L2E * WA[(8 + j) * 8 + k0];  wa2z[m].y = L2E * WA[(8 + j) * 8 + k1i];
        wa2c[m].x = T2E * WA[(16 + j) * 8 + k0]; wa2c[m].y = T2E * WA[(16 + j) * 8 + k1i];
        wb2r[m].x = mhi * L2E * Wih1[j * 8 + k0];        wb2r[m].y = mhi * L2E * Wih1[j * 8 + k1i];
        wb2z[m].x = mhi * L2E * Wih1[(8 + j) * 8 + k0];  wb2z[m].y = mhi * L2E * Wih1[(8 + j) * 8 + k1i];
        wb2c[m].x = mhi * T2E * Wih1[(16 + j) * 8 + k0]; wb2c[m].y = mhi * T2E * Wih1[(16 + j) * 8 + k1i];
    }
    const float base_r  = L2E * (layer ? (bih1[j] + bhh1[j])         : bhh0[j]);
    const float base_z  = L2E * (layer ? (bih1[8 + j] + bhh1[8 + j]) : bhh0[8 + j]);
    const float base_in = T2E * (layer ? bih1[16 + j]                : 0.f);
    const float base_dn = T2E * (layer ? bhh1[16 + j]                : bhh0[16 + j]);
    __syncthreads();   // once: xwg staged

    float hown = 0.f;
    float p0 = xwg[0][j], p1 = xwg[0][8 + j], p2 = xwg[0][16 + j];
#pragma unroll 1
    for (int t = 0; t <= 128; ++t) {
        int tn = t < 127 ? t + 1 : 127;
        float q0 = xwg[tn][j], q1 = xwg[tn][8 + j], q2 = xwg[tn][16 + j];
        // gather A (own-layer h rotations) and B (other-layer h rotations)
        float b0 = swzx16(hown);
        f2 A2[4], B2[4];
        A2[0].x = hown;           A2[0].y = rorf<1>(hown);
        A2[1].x = rorf<2>(hown);  A2[1].y = rorf<3>(hown);
        A2[2].x = rorf<4>(hown);  A2[2].y = rorf<5>(hown);
        A2[3].x = rorf<6>(hown);  A2[3].y = rorf<7>(hown);
        B2[0].x = b0;             B2[0].y = rorf<1>(b0);
        B2[1].x = rorf<2>(b0);    B2[1].y = rorf<3>(b0);
        B2[2].x = rorf<4>(b0);    B2[2].y = rorf<5>(b0);
        B2[3].x = rorf<6>(b0);    B2[3].y = rorf<7>(b0);

        f2 sra = wa2r[0] * A2[0], srb = wb2r[0] * B2[0];
        f2 sza = wa2z[0] * A2[0], szb = wb2z[0] * B2[0];
        f2 sca = wa2c[0] * A2[0], scb = wb2c[0] * B2[0];
#pragma unroll
        for (int m = 1; m < 4; ++m) {
            sra += wa2r[m] * A2[m];  srb += wb2r[m] * B2[m];
            sza += wa2z[m] * A2[m];  szb += wb2z[m] * B2[m];
            sca += wa2c[m] * A2[m];  scb += wb2c[m] * B2[m];
        }
        f2 sr = sra + srb, sz = sza + szb;
        float ar = fmaf(m0f, p0, base_r) + sr.x + sr.y;
        float az = fmaf(m0f, p1, base_z) + sz.x + sz.y;
        float acA = sca.x + sca.y;
        float acB = scb.x + scb.y;
        float r = fsig2(ar);
        float z = fsig2(az);
        float in_ = layer ? (base_in + acB) : p2;
        float dn  = base_dn + acA;
        float n = ftanh2(fmaf(r, dn, in_));
        float hnew = fmaf(z, hown - n, n);
        bool act = layer ? (t >= 1) : (t < 128);
        hown = act ? hnew : hown;
        if (tid >= 16 && tid < 24) h1all[t ? t - 1 : 0][j] = hown;
        p0 = q0; p1 = q1; p2 = q2;
    }
    __syncthreads();

    float* __restrict__ outp = ws + (track ? RO : LO);
    for (int t = tid; t < 128; t += 64) {
        float vv[8];
#pragma unroll
        for (int k = 0; k < 8; ++k) vv[k] = h1all[t][k];
        float mx = vv[0];
#pragma unroll
        for (int k = 1; k < 8; ++k) mx = fmaxf(mx, vv[k]);
        float ssum = 0.f;
#pragma unroll
        for (int k = 0; k < 8; ++k) { vv[k] = __expf(vv[k] - mx); ssum += vv[k]; }
        float inv = __builtin_amdgcn_rcpf(ssum);
        size_t base = ((size_t)b * 128 + t) * 8;
        float4 o0 = make_float4(vv[0] * inv, vv[1] * inv, vv[2] * inv, vv[3] * inv);
        float4 o1 = make_float4(vv[4] * inv, vv[5] * inv, vv[6] * inv, vv[7] * inv);
        *(float4*)(outp + base) = o0;
        *(float4*)(outp + base + 4) = o1;
    }
}

// ====== K2: expert layer-1 GEMM + gate mix + batch-stat accumulation ======
__global__ __launch_bounds__(256) void k2_expert1(
    const float* __restrict__ Local, const float* __restrict__ Remote,
    const float* __restrict__ ae_w1, const float* __restrict__ ae_b1,
    float* __restrict__ ws)
{
    const int blk = blockIdx.x;
    const int track = blk >> 7;
    const int n0 = (blk & 127) * 64;
    const float* __restrict__ X = track ? Remote : Local;
    const float* __restrict__ om = ws + (track ? RO : LO);

    __shared__ __align__(16) float xsh[64 * 132];     // row stride 132
    __shared__ __align__(16) float wsh[16 * 1060];    // [h][e][132]
    __shared__ float omsh[64][8];
    __shared__ float b1sh[128];
    __shared__ float red[32];
    const int tid = threadIdx.x;

    for (int i = tid; i < 2048; i += 256) {
        int r = i >> 5, q = i & 31;
        ((float4*)&xsh[r * 132])[q] = ((const float4*)(X + (size_t)(n0 + r) * 132))[q];
    }
    for (int i4 = tid; i4 < 4096; i4 += 256) {
        float4 v = ((const float4*)ae_w1)[i4];
        int i = i4 * 4;
#pragma unroll
        for (int c = 0; c < 4; ++c) {
            int ii = i + c;
            int h = ii & 15, kk = (ii >> 4) & 127, e = ii >> 11;
            float vc = c == 0 ? v.x : c == 1 ? v.y : c == 2 ? v.z : v.w;
            wsh[h * 1060 + e * 132 + kk] = vc;
        }
    }
    for (int i = tid; i < 512; i += 256) omsh[i >> 3][i & 7] = om[(size_t)(n0 + (i >> 3)) * 8 + (i & 7)];
    for (int i = tid; i < 128; i += 256) b1sh[i] = ae_b1[i];
    if (tid < 32) red[tid] = 0.f;
    __syncthreads();

    const int hh = tid & 15, rg = tid >> 4;
    float acc[4][8];
#pragma unroll
    for (int r = 0; r < 4; ++r)
#pragma unroll
        for (int e = 0; e < 8; ++e) acc[r][e] = 0.f;

#pragma unroll 4
    for (int kq = 0; kq < 32; ++kq) {
        float4 xv[4], wv[8];
#pragma unroll
        for (int r = 0; r < 4; ++r) xv[r] = *(const float4*)&xsh[(rg * 4 + r) * 132 + kq * 4];
#pragma unroll
        for (int e = 0; e < 8; ++e) wv[e] = *(const float4*)&wsh[hh * 1060 + e * 132 + kq * 4];
#pragma unroll
        for (int r = 0; r < 4; ++r)
#pragma unroll
            for (int e = 0; e < 8; ++e) {
                float a = acc[r][e];
                a = fmaf(xv[r].x, wv[e].x, a);
                a = fmaf(xv[r].y, wv[e].y, a);
                a = fmaf(xv[r].z, wv[e].z, a);
                a = fmaf(xv[r].w, wv[e].w, a);
                acc[r][e] = a;
            }
    }

    float s = 0.f, s2 = 0.f;
    float* __restrict__ hout = ws + HBUF + (size_t)track * 131072;
#pragma unroll
    for (int r = 0; r < 4; ++r) {
        int row = rg * 4 + r;
        float hv = 0.f;
#pragma unroll
        for (int e = 0; e < 8; ++e) hv = fmaf(omsh[row][e], acc[r][e] + b1sh[e * 16 + hh], hv);
        hout[(size_t)(n0 + row) * 16 + hh] = hv;
        s += hv; s2 += hv * hv;
    }
    __syncthreads();
    atomicAdd(&red[hh], s);
    atomicAdd(&red[16 + hh], s2);
    __syncthreads();
    if (tid < 32) atomicAdd(&ws[ACC + track * 32 + tid], red[tid]);
}

// ===== K3: phase A standalone — BN+ELU+MLP2+xw0, 256 blocks (s x quarter) =====
__global__ __launch_bounds__(256) void k3_phaseA(
    const float* __restrict__ ae_w2, const float* __restrict__ ae_b2,
    const float* __restrict__ ae_g, const float* __restrict__ ae_bt,
    const float* __restrict__ mWih0, const float* __restrict__ mbih0,
    float* __restrict__ ws)
{
    const int blk = blockIdx.x;
    const int s = blk >> 2;            // sequence 0..63
    const int r0 = (blk & 3) * 32;     // row quarter
    const int tid = threadIdx.x;

    __shared__ float stat[4][16];
    __shared__ __align__(16) float w2t[16 * 132];     // [o][e*16+h]
    __shared__ float b2sh[128];
    __shared__ float omsh[2][32][8];
    __shared__ __align__(16) float actsh[2][32][16];
    __shared__ __align__(16) float zsh[32][20];
    __shared__ __align__(16) float wihsh[48][20];
    __shared__ float bihsh[48];

    if (tid < 32) {
        int trk = tid >> 4, h = tid & 15;
        float sm = ws[ACC + trk * 32 + h], s2 = ws[ACC + trk * 32 + 16 + h];
        float m = sm * (1.f / 8192.f);
        float v = fmaxf(s2 * (1.f / 8192.f) - m * m, 0.f);
        stat[trk * 2][h] = m;
        stat[trk * 2 + 1][h] = rsqrtf(v + 1e-5f);
    }
    for (int i = tid; i < 2048; i += 256) {
        int e = i >> 8, h = (i >> 4) & 15, o = i & 15;
        w2t[o * 132 + e * 16 + h] = ae_w2[i];
    }
    for (int i = tid; i < 128; i += 256) b2sh[i] = ae_b2[i];
    for (int i = tid; i < 768; i += 256) wihsh[i >> 4][i & 15] = mWih0[i];
    if (tid < 48) bihsh[tid] = mbih0[tid];
    for (int i = tid; i < 512; i += 256) {
        int trk = i >> 8, r = (i >> 3) & 31, e = i & 7;
        omsh[trk][r][e] = ws[(trk ? RO : LO) + ((size_t)s * 128 + r0 + r) * 8 + e];
    }
    __syncthreads();

    for (int i = tid; i < 1024; i += 256) {
        int trk = i >> 9, r = (i >> 4) & 31, h = i & 15;
        float v = ws[HBUF + (size_t)trk * 131072 + ((size_t)s * 128 + r0 + r) * 16 + h];
        float a = ae_g[h] * (v - stat[trk * 2][h]) * stat[trk * 2 + 1][h] + ae_bt[h];
        actsh[trk][r][h] = a > 0.f ? a : expm1f(a);
    }
    __syncthreads();

    // zsh GEMM: thread -> (o = tid&15, rows 2*rb, 2*rb+1)
    {
        const int o = tid & 15, rb = tid >> 4;
        float zacc[2] = {0.f, 0.f};
#pragma unroll
        for (int ec = 0; ec < 2; ++ec) {
            float4 wv[4][4];
            float bo[4];
#pragma unroll
            for (int e4 = 0; e4 < 4; ++e4) {
                bo[e4] = b2sh[(ec * 4 + e4) * 16 + o];
#pragma unroll
                for (int q = 0; q < 4; ++q)
                    wv[e4][q] = *(const float4*)&w2t[o * 132 + (ec * 4 + e4) * 16 + q * 4];
            }
#pragma unroll
            for (int r2 = 0; r2 < 2; ++r2) {
                int r = rb * 2 + r2;
#pragma unroll
                for (int trk = 0; trk < 2; ++trk) {
                    float4 av[4];
#pragma unroll
                    for (int q = 0; q < 4; ++q) av[q] = *(const float4*)&actsh[trk][r][q * 4];
#pragma unroll
                    for (int e4 = 0; e4 < 4; ++e4) {
                        int e = ec * 4 + e4;
                        float t = bo[e4];
                        t = fmaf(av[0].x, wv[e4][0].x, t);
                        t = fmaf(av[0].y, wv[e4][0].y, t);
                        t = fmaf(av[0].z, wv[e4][0].z, t);
                        t = fmaf(av[0].w, wv[e4][0].w, t);
                        t = fmaf(av[1].x, wv[e4][1].x, t);
                        t = fmaf(av[1].y, wv[e4][1].y, t);
                        t = fmaf(av[1].z, wv[e4][1].z, t);
                        t = fmaf(av[1].w, wv[e4][1].w, t);
                        t = fmaf(av[2].x, wv[e4][2].x, t);
                        t = fmaf(av[2].y, wv[e4][2].y, t);
                        t = fmaf(av[2].z, wv[e4][2].z, t);
                        t = fmaf(av[2].w, wv[e4][2].w, t);
                        t = fmaf(av[3].x, wv[e4][3].x, t);
                        t = fmaf(av[3].y, wv[e4][3].y, t);
                        t = fmaf(av[3].z, wv[e4][3].z, t);
                        t = fmaf(av[3].w, wv[e4][3].w, t);
                        zacc[r2] = fmaf(omsh[trk][r][e], t, zacc[r2]);
                    }
                }
            }
        }
#pragma unroll
        for (int r2 = 0; r2 < 2; ++r2) zsh[rb * 2 + r2][o] = zacc[r2];
    }
    __syncthreads();

    // xw: thread -> (r = tid>>3 in 0..31, 6 gates at (tid&7)*6)
    {
        const int r = tid >> 3, g0 = (tid & 7) * 6;
        float4 zv[4];
#pragma unroll
        for (int q = 0; q < 4; ++q) zv[q] = *(const float4*)&zsh[r][q * 4];
        float* __restrict__ xwp = ws + XW + ((size_t)s * 128 + r0 + r) * 48;
#pragma unroll
        for (int gg = 0; gg < 6; ++gg) {
            int g = g0 + gg;
            float a = bihsh[g];
#pragma unroll
            for (int q = 0; q < 4; ++q) {
                float4 wv = *(const float4*)&wihsh[g][q * 4];
                a = fmaf(zv[q].x, wv.x, a);
                a = fmaf(zv[q].y, wv.y, a);
                a = fmaf(zv[q].z, wv.z, a);
                a = fmaf(zv[q].w, wv.w, a);
            }
            xwp[g] = a * (g < 32 ? L2E : T2E);
        }
    }
}

// ===== K4: main GRU recurrence standalone, 64 blocks x 64 thr, DPP broadcast =====
// rows: 0/2 = layer0 (h0), 1/3 = layer1 (h1). j = tid&15.
__global__ __launch_bounds__(64, 1) void k4_rec(
    const float* __restrict__ Whh0, const float* __restrict__ bhh0,
    const float* __restrict__ Wih1, const float* __restrict__ Whh1,
    const float* __restrict__ bih1, const float* __restrict__ bhh1,
    float* __restrict__ ws)
{
    const int s = blockIdx.x;
    const int tid = threadIdx.x;
    __shared__ __align__(16) float xwsh[128 * 48];

    const float4* __restrict__ xwg = (const float4*)(ws + XW + (size_t)s * 6144);
    for (int i = tid; i < 1536; i += 64) ((float4*)xwsh)[i] = xwg[i];

    const int j = tid & 15;
    const int layer = (tid >> 4) & 1;

    // A = own-layer h (Whh of own layer); B = other-layer h (Wih1, layer1 only)
    const float* __restrict__ WA = layer ? Whh1 : Whh0;
    const float mhi = layer ? 1.f : 0.f;
    const float m0f = layer ? 0.f : 1.f;
    f2 wa2r[8], wa2z[8], wa2c[8], wb2r[8], wb2z[8], wb2c[8];
#pragma unroll
    for (int m = 0; m < 8; ++m) {
        int k0 = (j - 2 * m) & 15, k1i = (j - 2 * m - 1) & 15;
        wa2r[m].x = L2E * WA[j * 16 + k0];        wa2r[m].y = L2E * WA[j * 16 + k1i];
        wa2z[m].x = L2E * WA[(16 + j) * 16 + k0]; wa2z[m].y = L2E * WA[(16 + j) * 16 + k1i];
        wa2c[m].x = T2E * WA[(32 + j) * 16 + k0]; wa2c[m].y = T2E * WA[(32 + j) * 16 + k1i];
        wb2r[m].x = mhi * L2E * Wih1[j * 16 + k0];        wb2r[m].y = mhi * L2E * Wih1[j * 16 + k1i];
        wb2z[m].x = mhi * L2E * Wih1[(16 + j) * 16 + k0]; wb2z[m].y = mhi * L2E * Wih1[(16 + j) * 16 + k1i];
        wb2c[m].x = mhi * T2E * Wih1[(32 + j) * 16 + k0]; wb2c[m].y = mhi * T2E * Wih1[(32 + j) * 16 + k1i];
    }
    const float base_r  = L2E * (layer ? (bih1[j] + bhh1[j])           : bhh0[j]);
    const float base_z  = L2E * (layer ? (bih1[16 + j] + bhh1[16 + j]) : bhh0[16 + j]);
    const float base_in = T2E * (layer ? bih1[32 + j]                  : 0.f);
    const float base_dn = T2E * (layer ? bhh1[32 + j]                  : bhh0[32 + j]);
    __syncthreads();

    float hown = 0.f;
    float p0 = xwsh[j], p1 = xwsh[16 + j], p2 = xwsh[32 + j];
#pragma unroll 1
    for (int t = 0; t <= 128; ++t) {
        int tn = (t < 127 ? t + 1 : 127) * 48;
        float q0 = xwsh[tn + j], q1 = xwsh[tn + 16 + j], q2 = xwsh[tn + 32 + j];
        float b0 = swzx16(hown);
        f2 A2[8], B2[8];
        A2[0].x = hown;            A2[0].y = rorf<1>(hown);
        A2[1].x = rorf<2>(hown);   A2[1].y = rorf<3>(hown);
        A2[2].x = rorf<4>(hown);   A2[2].y = rorf<5>(hown);
        A2[3].x = rorf<6>(hown);   A2[3].y = rorf<7>(hown);
        A2[4].x = rorf<8>(hown);   A2[4].y = rorf<9>(hown);
        A2[5].x = rorf<10>(hown);  A2[5].y = rorf<11>(hown);
        A2[6].x = rorf<12>(hown);  A2[6].y = rorf<13>(hown);
        A2[7].x = rorf<14>(hown);  A2[7].y = rorf<15>(hown);
        B2[0].x = b0;              B2[0].y = rorf<1>(b0);
        B2[1].x = rorf<2>(b0);     B2[1].y = rorf<3>(b0);
        B2[2].x = rorf<4>(b0);     B2[2].y = rorf<5>(b0);
        B2[3].x = rorf<6>(b0);     B2[3].y = rorf<7>(b0);
        B2[4].x = rorf<8>(b0);     B2[4].y = rorf<9>(b0);
        B2[5].x = rorf<10>(b0);    B2[5].y = rorf<11>(b0);
        B2[6].x = rorf<12>(b0);    B2[6].y = rorf<13>(b0);
        B2[7].x = rorf<14>(b0);    B2[7].y = rorf<15>(b0);

        f2 sra = wa2r[0] * A2[0], srb = wb2r[0] * B2[0];
        f2 sza = wa2z[0] * A2[0], szb = wb2z[0] * B2[0];
        f2 sca = wa2c[0] * A2[0], scb = wb2c[0] * B2[0];
#pragma unroll
        for (int m = 1; m < 8; ++m) {
            sra += wa2r[m] * A2[m];  srb += wb2r[m] * B2[m];
            sza += wa2z[m] * A2[m];  szb += wb2z[m] * B2[m];
            sca += wa2c[m] * A2[m];  scb += wb2c[m] * B2[m];
        }
        f2 sr = sra + srb, sz = sza + szb;
        float ar = fmaf(m0f, p0, base_r) + sr.x + sr.y;
        float az = fmaf(m0f, p1, base_z) + sz.x + sz.y;
        float acA = sca.x + sca.y;
        float acB = scb.x + scb.y;
        float r = fsig2(ar);
        float z = fsig2(az);
        float in_ = layer ? (base_in + acB) : p2;
        float dn  = base_dn + acA;
        float n = ftanh2(fmaf(r, dn, in_));
        float hnew = fmaf(z, hown - n, n);
        bool act = layer ? (t >= 1) : (t < 128);
        hown = act ? hnew : hown;
        p0 = q0; p1 = q1; p2 = q2;
    }
    if (tid >= 16 && tid < 32) ws[ZLAST + (size_t)s * 16 + j] = hown;
}

// ===== K34 fallback: fused phase A + phase B (used if ws too small) =====
__global__ __launch_bounds__(256, 1) void k34_fused(
    const float* __restrict__ ae_w2, const float* __restrict__ ae_b2,
    const float* __restrict__ ae_g, const float* __restrict__ ae_bt,
    const float* __restrict__ mWih0, const float* __restrict__ mbih0,
    const float* __restrict__ Whh0, const float* __restrict__ bhh0,
    const float* __restrict__ Wih1, const float* __restrict__ Whh1,
    const float* __restrict__ bih1, const float* __restrict__ bhh1,
    float* __restrict__ ws)
{
    const int s = blockIdx.x;
    const int tid = threadIdx.x;

    __shared__ float stat[4][16];
    __shared__ float omsh[2][128][8];
    __shared__ __align__(16) float w2t[16 * 132];
    __shared__ float b2sh[128];
    __shared__ __align__(16) float actsh[2][128][16];
    __shared__ __align__(16) float zsh[128][20];
    __shared__ __align__(16) float wihsh[48][20];
    __shared__ float bihsh[48];
    __shared__ float xwsh[128 * 48];

    if (tid < 32) {
        int trk = tid >> 4, h = tid & 15;
        float sm = ws[ACC + trk * 32 + h], s2 = ws[ACC + trk * 32 + 16 + h];
        float m = sm * (1.f / 8192.f);
        float v = fmaxf(s2 * (1.f / 8192.f) - m * m, 0.f);
        stat[trk * 2][h] = m;
        stat[trk * 2 + 1][h] = rsqrtf(v + 1e-5f);
    }
    for (int i = tid; i < 2048; i += 256) {
        int e = i >> 8, h = (i >> 4) & 15, o = i & 15;
        w2t[o * 132 + e * 16 + h] = ae_w2[i];
    }
    for (int i = tid; i < 128; i += 256) b2sh[i] = ae_b2[i];
    for (int i = tid; i < 768; i += 256) wihsh[i >> 4][i & 15] = mWih0[i];
    if (tid < 48) bihsh[tid] = mbih0[tid];
    for (int i = tid; i < 2048; i += 256) {
        int trk = i >> 10, r = (i >> 3) & 127, e = i & 7;
        omsh[trk][r][e] = ws[(trk ? RO : LO) + ((size_t)s * 128 + r) * 8 + e];
    }
    __syncthreads();

    for (int i = tid; i < 4096; i += 256) {
        int trk = i >> 11, r = (i >> 4) & 127, h = i & 15;
        float v = ws[HBUF + (size_t)trk * 131072 + ((size_t)s * 128 + r) * 16 + h];
        float a = ae_g[h] * (v - stat[trk * 2][h]) * stat[trk * 2 + 1][h] + ae_bt[h];
        actsh[trk][r][h] = a > 0.f ? a : expm1f(a);
    }
    __syncthreads();

    {
        const int o = tid & 15, rb = tid >> 4;
        float zacc[8];
#pragma unroll
        for (int r8 = 0; r8 < 8; ++r8) zacc[r8] = 0.f;
#pragma unroll
        for (int ec = 0; ec < 2; ++ec) {
            float4 wv[4][4];
#pragma unroll
            for (int e4 = 0; e4 < 4; ++e4)
#pragma unroll
                for (int q = 0; q < 4; ++q)
                    wv[e4][q] = *(const float4*)&w2t[o * 132 + (ec * 4 + e4) * 16 + q * 4];
#pragma unroll
            for (int r8 = 0; r8 < 8; ++r8) {
                int r = rb * 8 + r8;
#pragma unroll
                for (int trk = 0; trk < 2; ++trk) {
                    float4 av[4];
#pragma unroll
                    for (int q = 0; q < 4; ++q) av[q] = *(const float4*)&actsh[trk][r][q * 4];
#pragma unroll
                    for (int e4 = 0; e4 < 4; ++e4) {
                        int e = ec * 4 + e4;
                        float t = b2sh[e * 16 + o];
                        t = fmaf(av[0].x, wv[e4][0].x, t);
                        t = fmaf(av[0].y, wv[e4][0].y, t);
                        t = fmaf(av[0].z, wv[e4][0].z, t);
                        t = fmaf(av[0].w, wv[e4][0].w, t);
                        t = fmaf(av[1].x, wv[e4][1].x, t);
                        t = fmaf(av[1].y, wv[e4][1].y, t);
                        t = fmaf(av[1].z, wv[e4][1].z, t);
                        t = fmaf(av[1].w, wv[e4][1].w, t);
                        t = fmaf(av[2].x, wv[e4][2].x, t);
                        t = fmaf(av[2].y, wv[e4][2].y, t);
                        t = fmaf(av[2].z, wv[e4][2].z, t);
                        t = fmaf(av[2].w, wv[e4][2].w, t);
                        t = fmaf(av[3].x, wv[e4][3].x, t);
                        t = fmaf(av[3].y, wv[e4][3].y, t);
                        t = fmaf(av[3].z, wv[e4][3].z, t);
                        t = fmaf(av[3].w, wv[e4][3].w, t);
                        zacc[r8] = fmaf(omsh[trk][r][e], t, zacc[r8]);
                    }
                }
            }
        }
#pragma unroll
        for (int r8 = 0; r8 < 8; ++r8) zsh[rb * 8 + r8][o] = zacc[r8];
    }
    __syncthreads();

    {
        const int r = tid >> 1, gh = (tid & 1) * 24;
        float4 zv[4];
#pragma unroll
        for (int q = 0; q < 4; ++q) zv[q] = *(const float4*)&zsh[r][q * 4];
#pragma unroll
        for (int gg = 0; gg < 24; ++gg) {
            int g = gh + gg;
            float a = bihsh[g];
#pragma unroll
            for (int q = 0; q < 4; ++q) {
                float4 wv = *(const float4*)&wihsh[g][q * 4];
                a = fmaf(zv[q].x, wv.x, a);
                a = fmaf(zv[q].y, wv.y, a);
                a = fmaf(zv[q].z, wv.z, a);
                a = fmaf(zv[q].w, wv.w, a);
            }
            xwsh[r * 48 + g] = a * (g < 32 ? L2E : T2E);
        }
    }
    __syncthreads();

    if (tid >= 64) return;

    const int j = tid & 15;
    const int layer = (tid >> 4) & 1;

    const float* __restrict__ Wlo = layer ? Wih1 : Whh0;
    const float mhi = layer ? 1.f : 0.f;
    const float m0f = layer ? 0.f : 1.f;
    f2 wr2[16], wz2[16], wc2[16];
#pragma unroll
    for (int m = 0; m < 8; ++m) {
        wr2[m].x = L2E * Wlo[j * 16 + 2 * m];
        wr2[m].y = L2E * Wlo[j * 16 + 2 * m + 1];
        wz2[m].x = L2E * Wlo[(16 + j) * 16 + 2 * m];
        wz2[m].y = L2E * Wlo[(16 + j) * 16 + 2 * m + 1];
        wc2[m].x = T2E * Wlo[(32 + j) * 16 + 2 * m];
        wc2[m].y = T2E * Wlo[(32 + j) * 16 + 2 * m + 1];
        wr2[8 + m].x = mhi * L2E * Whh1[j * 16 + 2 * m];
        wr2[8 + m].y = mhi * L2E * Whh1[j * 16 + 2 * m + 1];
        wz2[8 + m].x = mhi * L2E * Whh1[(16 + j) * 16 + 2 * m];
        wz2[8 + m].y = mhi * L2E * Whh1[(16 + j) * 16 + 2 * m + 1];
        wc2[8 + m].x = mhi * T2E * Whh1[(32 + j) * 16 + 2 * m];
        wc2[8 + m].y = mhi * T2E * Whh1[(32 + j) * 16 + 2 * m + 1];
    }
    const float base_r  = L2E * (layer ? (bih1[j] + bhh1[j])           : bhh0[j]);
    const float base_z  = L2E * (layer ? (bih1[16 + j] + bhh1[16 + j]) : bhh0[16 + j]);
    const float base_in = T2E * (layer ? bih1[32 + j]                  : 0.f);
    const float base_dn = T2E * (layer ? bhh1[32 + j]                  : bhh0[32 + j]);

    float hown = 0.f;
    float p0 = xwsh[j], p1 = xwsh[16 + j], p2 = xwsh[32 + j];
#pragma unroll 1
    for (int t = 0; t <= 128; ++t) {
        int tn = (t < 127 ? t + 1 : 127) * 48;
        float q0 = xwsh[tn + j], q1 = xwsh[tn + 16 + j], q2 = xwsh[tn + 32 + j];
        f2 vb2[16];
#pragma unroll
        for (int m = 0; m < 16; ++m) {
            vb2[m].x = readlanef(hown, 2 * m);
            vb2[m].y = readlanef(hown, 2 * m + 1);
        }
        f2 srE = wr2[0] * vb2[0], srO = wr2[1] * vb2[1];
        f2 szE = wz2[0] * vb2[0], szO = wz2[1] * vb2[1];
#pragma unroll
        for (int m = 2; m < 16; m += 2) {
            srE += wr2[m] * vb2[m];     srO += wr2[m + 1] * vb2[m + 1];
            szE += wz2[m] * vb2[m];     szO += wz2[m + 1] * vb2[m + 1];
        }
        f2 scA = wc2[0] * vb2[0], scB = wc2[1] * vb2[1];
        f2 scC = wc2[8] * vb2[8], scD = wc2[9] * vb2[9];
#pragma unroll
        for (int m = 2; m < 8; m += 2) {
            scA += wc2[m] * vb2[m];         scB += wc2[m + 1] * vb2[m + 1];
            scC += wc2[8 + m] * vb2[8 + m]; scD += wc2[9 + m] * vb2[9 + m];
        }
        f2 sr = srE + srO, sz = szE + szO;
        f2 scL = scA + scB, scH = scC + scD;
        float ar = fmaf(m0f, p0, base_r) + sr.x + sr.y;
        float az = fmaf(m0f, p1, base_z) + sz.x + sz.y;
        float ac_lo = scL.x + scL.y;
        float ac_hi = scH.x + scH.y;
        float r = fsig2(ar);
        float z = fsig2(az);
        float in_ = layer ? (base_in + ac_lo) : p2;
        float dn  = base_dn + (layer ? ac_hi : ac_lo);
        float n = ftanh2(fmaf(r, dn, in_));
        float hnew = fmaf(z, hown - n, n);
        bool act = layer ? (t >= 1) : (t < 128);
        hown = act ? hnew : hown;
        p0 = q0; p1 = q1; p2 = q2;
    }
    if (tid >= 16 && tid < 32) ws[ZLAST + (size_t)s * 16 + j] = hown;
}

// ===== K5: decoder MLP fused (layer1+BN redundant per block, layer2 slice) =====
__global__ __launch_bounds__(256) void k5_dec(
    const float* __restrict__ Remote,
    const float* __restrict__ md_w1, const float* __restrict__ md_b1,
    const float* __restrict__ md_g, const float* __restrict__ md_bt,
    const float* __restrict__ md_w2, const float* __restrict__ md_b2,
    const float* __restrict__ ws, float* __restrict__ out)
{
    const int o0 = blockIdx.x * 8;
    const int tid = threadIdx.x;
    __shared__ float xsh[64][17];
    __shared__ float omsh[64][8];
    __shared__ float w1sh[2176];
    __shared__ float b1sh[128];
    __shared__ float hsh[64][17];
    __shared__ float ssum[16], ss2[16], mstat[2][16];
    __shared__ float ash[64][17];
    __shared__ float w2sh[8][16][8];
    __shared__ float b2sh[8][8];

    for (int i = tid; i < 1024; i += 256) xsh[i >> 4][i & 15] = ws[ZLAST + i];
    if (tid < 64) xsh[tid][16] = Remote[((size_t)tid * 128 + 127) * 132 + 131];
    for (int i = tid; i < 512; i += 256)
        omsh[i >> 3][i & 7] = ws[RO + ((size_t)(i >> 3) * 128 + 127) * 8 + (i & 7)];
    for (int i = tid; i < 2176; i += 256) w1sh[i] = md_w1[i];
    for (int i = tid; i < 128; i += 256) b1sh[i] = md_b1[i];
    for (int i = tid; i < 1024; i += 256) {
        int e = i >> 7, h = (i >> 3) & 15, oo = i & 7;
        w2sh[e][h][oo] = md_w2[((size_t)e * 16 + h) * 128 + o0 + oo];
    }
    if (tid < 64) b2sh[tid >> 3][tid & 7] = md_b2[(size_t)(tid >> 3) * 128 + o0 + (tid & 7)];
    if (tid < 16) { ssum[tid] = 0.f; ss2[tid] = 0.f; }
    __syncthreads();

    for (int i = tid; i < 1024; i += 256) {
        int b = i >> 4, h = i & 15;
        float accv = 0.f;
#pragma unroll
        for (int e = 0; e < 8; ++e) {
            float t = b1sh[e * 16 + h];
            const float* w = &w1sh[e * 272 + h];
#pragma unroll
            for (int i2 = 0; i2 < 17; ++i2) t = fmaf(xsh[b][i2], w[i2 * 16], t);
            accv = fmaf(omsh[b][e], t, accv);
        }
        hsh[b][h] = accv;
        atomicAdd(&ssum[h], accv);
        atomicAdd(&ss2[h], accv * accv);
    }
    __syncthreads();
    if (tid < 16) {
        float m = ssum[tid] * (1.f / 64.f);
        float v = fmaxf(ss2[tid] * (1.f / 64.f) - m * m, 0.f);
        mstat[0][tid] = m;
        mstat[1][tid] = rsqrtf(v + 1e-5f);
    }
    __syncthreads();
    for (int i = tid; i < 1024; i += 256) {
        int b = i >> 4, h = i & 15;
        float a = md_g[h] * (hsh[b][h] - mstat[0][h]) * mstat[1][h] + md_bt[h];
        ash[b][h] = a > 0.f ? a : expm1f(a);
    }
    __syncthreads();

    for (int i = tid; i < 512; i += 256) {
        int b = i >> 3, oo = i & 7;
        float accv = 0.f;
#pragma unroll
        for (int e = 0; e < 8; ++e) {
            float t = b2sh[e][oo];
#pragma unroll
            for (int h = 0; h < 16; ++h) t = fmaf(ash[b][h], w2sh[e][h][oo], t);
            accv = fmaf(omsh[b][e], t, accv);
        }
        out[(size_t)b * 128 + o0 + oo] = accv;
    }
}

extern "C" void kernel_launch(void* const* d_in, const int* in_sizes, int n_in,
                              void* d_out, int out_size, void* d_ws, size_t ws_size,
                              hipStream_t stream) {
    const float* Local  = (const float*)d_in[0];
    const float* Remote = (const float*)d_in[1];
    const float* gWih0  = (const float*)d_in[2];
    const float* gWhh0  = (const float*)d_in[3];
    const float* gbih0  = (const float*)d_in[4];
    const float* gbhh0  = (const float*)d_in[5];
    const float* gWih1  = (const float*)d_in[6];
    const float* gWhh1  = (const float*)d_in[7];
    const float* gbih1  = (const float*)d_in[8];
    const float* gbhh1  = (const float*)d_in[9];
    const float* mWih0  = (const float*)d_in[10];
    const float* mWhh0  = (const float*)d_in[11];
    const float* mbih0  = (const float*)d_in[12];
    const float* mbhh0  = (const float*)d_in[13];
    const float* mWih1  = (const float*)d_in[14];
    const float* mWhh1  = (const float*)d_in[15];
    const float* mbih1  = (const float*)d_in[16];
    const float* mbhh1  = (const float*)d_in[17];
    const float* ae_w1  = (const float*)d_in[18];
    const float* ae_b1  = (const float*)d_in[19];
    const float* ae_w2  = (const float*)d_in[20];
    const float* ae_b2  = (const float*)d_in[21];
    const float* ae_g   = (const float*)d_in[22];
    const float* ae_bt  = (const float*)d_in[23];
    const float* md_w1  = (const float*)d_in[24];
    const float* md_b1  = (const float*)d_in[25];
    const float* md_w2  = (const float*)d_in[26];
    const float* md_b2  = (const float*)d_in[27];
    const float* md_g   = (const float*)d_in[28];
    const float* md_bt  = (const float*)d_in[29];
    float* ws  = (float*)d_ws;
    float* out = (float*)d_out;

    k1_gate<<<128, 64, 0, stream>>>(Local, Remote, gWih0, gWhh0, gbih0, gbhh0,
                                    gWih1, gWhh1, gbih1, gbhh1, ws);
    k2_expert1<<<256, 256, 0, stream>>>(Local, Remote, ae_w1, ae_b1, ws);
    if (ws_size >= WS_NEED * sizeof(float)) {
        k3_phaseA<<<256, 256, 0, stream>>>(ae_w2, ae_b2, ae_g, ae_bt, mWih0, mbih0, ws);
        k4_rec<<<64, 64, 0, stream>>>(mWhh0, mbhh0, mWih1, mWhh1, mbih1, mbhh1, ws);
    } else {
        k34_fused<<<64, 256, 0, stream>>>(ae_w2, ae_b2, ae_g, ae_bt, mWih0, mbih0,
                                          mWhh0, mbhh0, mWih1, mWhh1, mbih1, mbhh1, ws);
    }
    k5_dec<<<16, 256, 0, stream>>>(Remote, md_w1, md_b1, md_g, md_bt,
                                   md_w2, md_b2, ws, out);
}

// Round 5
// 218.398 us; speedup vs baseline: 1.0511x; 1.0511x over previous
//
#include <hip/hip_runtime.h>
#include <cstdint>
#include <cstddef>

#define DEV __device__ __forceinline__

typedef float f2 __attribute__((ext_vector_type(2)));

constexpr float L2E = 1.4426950408889634f;   // log2(e)
constexpr float T2E = 2.8853900817779268f;   // 2*log2(e)

DEV float readlanef(float v, int l) {
    return __uint_as_float(__builtin_amdgcn_readlane(__float_as_uint(v), l));
}
// sigmoid(x) with pre-scaled argument y = L2E*x : 1/(1+2^-y)
DEV float fsig2(float y)  { return __builtin_amdgcn_rcpf(1.0f + __builtin_amdgcn_exp2f(-y)); }
// tanh(x) with pre-scaled argument y = 2*L2E*x : 1 - 2/(1+2^y)
DEV float ftanh2(float y) { return 1.0f - 2.0f * __builtin_amdgcn_rcpf(1.0f + __builtin_amdgcn_exp2f(y)); }

// DPP row rotate-right by N within each 16-lane row: dst[i] = src[(i-N)&15 of row]
template<int N> DEV float rorf(float v) {
    return __uint_as_float((unsigned)__builtin_amdgcn_mov_dpp(
        (int)__float_as_uint(v), 0x120 + N, 0xF, 0xF, false));
}
// ds_swizzle xor-16: dst[i] = src[i^16] (within each 32-lane half)
DEV float swzx16(float v) {
    return __uint_as_float((unsigned)__builtin_amdgcn_ds_swizzle(
        (int)__float_as_uint(v), 0x401F));
}

// ---------------- ws layout (float offsets) ----------------
constexpr size_t ACC   = 0;                 // 64  (2 tracks x (16 sum + 16 sumsq))
constexpr size_t LO    = 128;               // 65536  Lo[64][128][8]
constexpr size_t RO    = LO + 65536;        // 65536  Ro[64][128][8]
constexpr size_t HBUF  = RO + 65536;        // 262144 h[track][8192][16]
constexpr size_t ZLAST = HBUF + 262144;     // 1024   zlast[64][16]
constexpr size_t XWT   = ZLAST + 1024;      // 430080 xwT[64][48][140] (pre-scaled, transposed)
constexpr size_t WS_NEED = XWT + 430080;    // floats

// ===== K1: gate GRU, 1 seq/wave, skewed layers, DPP broadcast =====
// Transposed xw in LDS, chunked float4 reads, pipelined swizzle.
__global__ __launch_bounds__(64, 1) void k1_gate(
    const float* __restrict__ Local, const float* __restrict__ Remote,
    const float* __restrict__ Wih0, const float* __restrict__ Whh0,
    const float* __restrict__ bih0, const float* __restrict__ bhh0,
    const float* __restrict__ Wih1, const float* __restrict__ Whh1,
    const float* __restrict__ bih1, const float* __restrict__ bhh1,
    float* __restrict__ ws)
{
    const int tid = threadIdx.x;
    const int j = tid & 7;
    const int layer = (tid >> 4) & 1;
    const int blk = blockIdx.x;
    const int track = blk >> 6;
    const int b = blk & 63;
    if (blk == 0) ws[ACC + tid] = 0.f;

    __shared__ __align__(16) float xwgT[24 * 140];  // [gate][t] pre-scaled
    __shared__ float h1all[128][9];

    const float* __restrict__ src = track ? Remote : Local;
    for (int t = tid; t < 128; t += 64) {
        const float* p = src + ((size_t)b * 128 + t) * 132 + 128;
        float x0 = p[0], x1 = p[1], x2 = p[2];
#pragma unroll
        for (int u = 0; u < 24; ++u) {
            float a = bih0[u];
            a = fmaf(Wih0[u * 3 + 0], x0, a);
            a = fmaf(Wih0[u * 3 + 1], x1, a);
            a = fmaf(Wih0[u * 3 + 2], x2, a);
            xwgT[u * 140 + t] = a * (u < 16 ? L2E : T2E);
        }
    }
    // zero the tail cols 128..131 (read by the last chunk, must not be NaN)
    for (int i = tid; i < 96; i += 64) xwgT[(i >> 2) * 140 + 128 + (i & 3)] = 0.f;

    // A = own-layer h (Whh of own layer); B = other-layer h (Wih1, layer1 only)
    const float* __restrict__ WA = layer ? Whh1 : Whh0;
    const float mhi = layer ? 1.f : 0.f;
    const float m0f = layer ? 0.f : 1.f;
    f2 wa2r[4], wa2z[4], wa2c[4], wb2r[4], wb2z[4], wb2c[4];
#pragma unroll
    for (int m = 0; m < 4; ++m) {
        int k0 = (j - 2 * m) & 7, k1i = (j - 2 * m - 1) & 7;
        wa2r[m].x = L2E * WA[j * 8 + k0];        wa2r[m].y = L2E * WA[j * 8 + k1i];
        wa2z[m].x = L2E * WA[(8 + j) * 8 + k0];  wa2z[m].y = L2E * WA[(8 + j) * 8 + k1i];
        wa2c[m].x = T2E * WA[(16 + j) * 8 + k0]; wa2c[m].y = T2E * WA[(16 + j) * 8 + k1i];
        wb2r[m].x = mhi * L2E * Wih1[j * 8 + k0];        wb2r[m].y = mhi * L2E * Wih1[j * 8 + k1i];
        wb2z[m].x = mhi * L2E * Wih1[(8 + j) * 8 + k0];  wb2z[m].y = mhi * L2E * Wih1[(8 + j) * 8 + k1i];
        wb2c[m].x = mhi * T2E * Wih1[(16 + j) * 8 + k0]; wb2c[m].y = mhi * T2E * Wih1[(16 + j) * 8 + k1i];
    }
    const float base_r  = L2E * (layer ? (bih1[j] + bhh1[j])         : bhh0[j]);
    const float base_z  = L2E * (layer ? (bih1[8 + j] + bhh1[8 + j]) : bhh0[8 + j]);
    const float base_in = T2E * (layer ? bih1[16 + j]                : 0.f);
    const float base_dn = T2E * (layer ? bhh1[16 + j]                : bhh0[16 + j]);
    __syncthreads();   // once: xwgT staged

    float hown = 0.f, b0 = 0.f;
    float4 d0 = *(const float4*)&xwgT[j * 140];
    float4 d1 = *(const float4*)&xwgT[(8 + j) * 140];
    float4 d2 = *(const float4*)&xwgT[(16 + j) * 140];
    float4 n0v = *(const float4*)&xwgT[j * 140 + 4];
    float4 n1v = *(const float4*)&xwgT[(8 + j) * 140 + 4];
    float4 n2v = *(const float4*)&xwgT[(16 + j) * 140 + 4];
#pragma unroll 1
    for (int tc = 0; tc < 33; ++tc) {
        float4 e0 = d0, e1 = d1, e2 = d2;
        d0 = n0v; d1 = n1v; d2 = n2v;
        int nc = tc + 2; if (nc > 32) nc = 32;
        n0v = *(const float4*)&xwgT[j * 140 + nc * 4];
        n1v = *(const float4*)&xwgT[(8 + j) * 140 + nc * 4];
        n2v = *(const float4*)&xwgT[(16 + j) * 140 + nc * 4];
#pragma unroll
        for (int tt = 0; tt < 4; ++tt) {
            const int t = tc * 4 + tt;
            float p0 = tt == 0 ? e0.x : tt == 1 ? e0.y : tt == 2 ? e0.z : e0.w;
            float p1 = tt == 0 ? e1.x : tt == 1 ? e1.y : tt == 2 ? e1.z : e1.w;
            float p2 = tt == 0 ? e2.x : tt == 1 ? e2.y : tt == 2 ? e2.z : e2.w;
            f2 A2[4], B2[4];
            A2[0].x = hown;           A2[0].y = rorf<1>(hown);
            A2[1].x = rorf<2>(hown);  A2[1].y = rorf<3>(hown);
            A2[2].x = rorf<4>(hown);  A2[2].y = rorf<5>(hown);
            A2[3].x = rorf<6>(hown);  A2[3].y = rorf<7>(hown);
            B2[0].x = b0;             B2[0].y = rorf<1>(b0);
            B2[1].x = rorf<2>(b0);    B2[1].y = rorf<3>(b0);
            B2[2].x = rorf<4>(b0);    B2[2].y = rorf<5>(b0);
            B2[3].x = rorf<6>(b0);    B2[3].y = rorf<7>(b0);

            f2 sra = wa2r[0] * A2[0], srb = wb2r[0] * B2[0];
            f2 sza = wa2z[0] * A2[0], szb = wb2z[0] * B2[0];
            f2 sca = wa2c[0] * A2[0], scb = wb2c[0] * B2[0];
#pragma unroll
            for (int m = 1; m < 4; ++m) {
                sra += wa2r[m] * A2[m];  srb += wb2r[m] * B2[m];
                sza += wa2z[m] * A2[m];  szb += wb2z[m] * B2[m];
                sca += wa2c[m] * A2[m];  scb += wb2c[m] * B2[m];
            }
            f2 sr = sra + srb, sz = sza + szb;
            float ar = fmaf(m0f, p0, base_r) + sr.x + sr.y;
            float az = fmaf(m0f, p1, base_z) + sz.x + sz.y;
            float acA = sca.x + sca.y;
            float acB = scb.x + scb.y;
            float r = fsig2(ar);
            float z = fsig2(az);
            float in_ = layer ? (base_in + acB) : p2;
            float dn  = base_dn + acA;
            float n = ftanh2(fmaf(r, dn, in_));
            float hnew = fmaf(z, hown - n, n);
            bool act = layer ? (t >= 1 && t < 129) : (t < 128);
            hown = act ? hnew : hown;
            if (t >= 1 && t < 129 && tid >= 16 && tid < 24) h1all[t - 1][j] = hown;
            b0 = swzx16(hown);   // pipelined: consumed next iteration
        }
    }
    __syncthreads();

    float* __restrict__ outp = ws + (track ? RO : LO);
    for (int t = tid; t < 128; t += 64) {
        float vv[8];
#pragma unroll
        for (int k = 0; k < 8; ++k) vv[k] = h1all[t][k];
        float mx = vv[0];
#pragma unroll
        for (int k = 1; k < 8; ++k) mx = fmaxf(mx, vv[k]);
        float ssum = 0.f;
#pragma unroll
        for (int k = 0; k < 8; ++k) { vv[k] = __expf(vv[k] - mx); ssum += vv[k]; }
        float inv = __builtin_amdgcn_rcpf(ssum);
        size_t base = ((size_t)b * 128 + t) * 8;
        float4 o0 = make_float4(vv[0] * inv, vv[1] * inv, vv[2] * inv, vv[3] * inv);
        float4 o1 = make_float4(vv[4] * inv, vv[5] * inv, vv[6] * inv, vv[7] * inv);
        *(float4*)(outp + base) = o0;
        *(float4*)(outp + base + 4) = o1;
    }
}

// ====== K2: expert layer-1 GEMM + gate mix + batch-stat accumulation ======
__global__ __launch_bounds__(256) void k2_expert1(
    const float* __restrict__ Local, const float* __restrict__ Remote,
    const float* __restrict__ ae_w1, const float* __restrict__ ae_b1,
    float* __restrict__ ws)
{
    const int blk = blockIdx.x;
    const int track = blk >> 7;
    const int n0 = (blk & 127) * 64;
    const float* __restrict__ X = track ? Remote : Local;
    const float* __restrict__ om = ws + (track ? RO : LO);

    __shared__ __align__(16) float xsh[64 * 132];     // row stride 132
    __shared__ __align__(16) float wsh[16 * 1060];    // [h][e][132]
    __shared__ float omsh[64][8];
    __shared__ float b1sh[128];
    __shared__ float red[32];
    const int tid = threadIdx.x;

    for (int i = tid; i < 2048; i += 256) {
        int r = i >> 5, q = i & 31;
        ((float4*)&xsh[r * 132])[q] = ((const float4*)(X + (size_t)(n0 + r) * 132))[q];
    }
    for (int i4 = tid; i4 < 4096; i4 += 256) {
        float4 v = ((const float4*)ae_w1)[i4];
        int i = i4 * 4;
#pragma unroll
        for (int c = 0; c < 4; ++c) {
            int ii = i + c;
            int h = ii & 15, kk = (ii >> 4) & 127, e = ii >> 11;
            float vc = c == 0 ? v.x : c == 1 ? v.y : c == 2 ? v.z : v.w;
            wsh[h * 1060 + e * 132 + kk] = vc;
        }
    }
    for (int i = tid; i < 512; i += 256) omsh[i >> 3][i & 7] = om[(size_t)(n0 + (i >> 3)) * 8 + (i & 7)];
    for (int i = tid; i < 128; i += 256) b1sh[i] = ae_b1[i];
    if (tid < 32) red[tid] = 0.f;
    __syncthreads();

    const int hh = tid & 15, rg = tid >> 4;
    float acc[4][8];
#pragma unroll
    for (int r = 0; r < 4; ++r)
#pragma unroll
        for (int e = 0; e < 8; ++e) acc[r][e] = 0.f;

#pragma unroll 4
    for (int kq = 0; kq < 32; ++kq) {
        float4 xv[4], wv[8];
#pragma unroll
        for (int r = 0; r < 4; ++r) xv[r] = *(const float4*)&xsh[(rg * 4 + r) * 132 + kq * 4];
#pragma unroll
        for (int e = 0; e < 8; ++e) wv[e] = *(const float4*)&wsh[hh * 1060 + e * 132 + kq * 4];
#pragma unroll
        for (int r = 0; r < 4; ++r)
#pragma unroll
            for (int e = 0; e < 8; ++e) {
                float a = acc[r][e];
                a = fmaf(xv[r].x, wv[e].x, a);
                a = fmaf(xv[r].y, wv[e].y, a);
                a = fmaf(xv[r].z, wv[e].z, a);
                a = fmaf(xv[r].w, wv[e].w, a);
                acc[r][e] = a;
            }
    }

    float s = 0.f, s2 = 0.f;
    float* __restrict__ hout = ws + HBUF + (size_t)track * 131072;
#pragma unroll
    for (int r = 0; r < 4; ++r) {
        int row = rg * 4 + r;
        float hv = 0.f;
#pragma unroll
        for (int e = 0; e < 8; ++e) hv = fmaf(omsh[row][e], acc[r][e] + b1sh[e * 16 + hh], hv);
        hout[(size_t)(n0 + row) * 16 + hh] = hv;
        s += hv; s2 += hv * hv;
    }
    __syncthreads();
    atomicAdd(&red[hh], s);
    atomicAdd(&red[16 + hh], s2);
    __syncthreads();
    if (tid < 32) atomicAdd(&ws[ACC + track * 32 + tid], red[tid]);
}

// ===== K3: phase A standalone — BN+ELU+MLP2+xw0 (transposed out), 256 blocks =====
__global__ __launch_bounds__(256) void k3_phaseA(
    const float* __restrict__ ae_w2, const float* __restrict__ ae_b2,
    const float* __restrict__ ae_g, const float* __restrict__ ae_bt,
    const float* __restrict__ mWih0, const float* __restrict__ mbih0,
    float* __restrict__ ws)
{
    const int blk = blockIdx.x;
    const int s = blk >> 2;            // sequence 0..63
    const int r0 = (blk & 3) * 32;     // row quarter
    const int tid = threadIdx.x;

    __shared__ float stat[4][16];
    __shared__ __align__(16) float w2t[16 * 132];     // [o][e*16+h]
    __shared__ float b2sh[128];
    __shared__ float omsh[2][32][8];
    __shared__ __align__(16) float actsh[2][32][16];
    __shared__ __align__(16) float zsh[32][20];
    __shared__ __align__(16) float wihsh[48][20];
    __shared__ float bihsh[48];

    if (tid < 32) {
        int trk = tid >> 4, h = tid & 15;
        float sm = ws[ACC + trk * 32 + h], s2 = ws[ACC + trk * 32 + 16 + h];
        float m = sm * (1.f / 8192.f);
        float v = fmaxf(s2 * (1.f / 8192.f) - m * m, 0.f);
        stat[trk * 2][h] = m;
        stat[trk * 2 + 1][h] = rsqrtf(v + 1e-5f);
    }
    for (int i = tid; i < 2048; i += 256) {
        int e = i >> 8, h = (i >> 4) & 15, o = i & 15;
        w2t[o * 132 + e * 16 + h] = ae_w2[i];
    }
    for (int i = tid; i < 128; i += 256) b2sh[i] = ae_b2[i];
    for (int i = tid; i < 768; i += 256) wihsh[i >> 4][i & 15] = mWih0[i];
    if (tid < 48) bihsh[tid] = mbih0[tid];
    for (int i = tid; i < 512; i += 256) {
        int trk = i >> 8, r = (i >> 3) & 31, e = i & 7;
        omsh[trk][r][e] = ws[(trk ? RO : LO) + ((size_t)s * 128 + r0 + r) * 8 + e];
    }
    __syncthreads();

    for (int i = tid; i < 1024; i += 256) {
        int trk = i >> 9, r = (i >> 4) & 31, h = i & 15;
        float v = ws[HBUF + (size_t)trk * 131072 + ((size_t)s * 128 + r0 + r) * 16 + h];
        float a = ae_g[h] * (v - stat[trk * 2][h]) * stat[trk * 2 + 1][h] + ae_bt[h];
        actsh[trk][r][h] = a > 0.f ? a : expm1f(a);
    }
    __syncthreads();

    // zsh GEMM: thread -> (o = tid&15, rows 2*rb, 2*rb+1)
    {
        const int o = tid & 15, rb = tid >> 4;
        float zacc[2] = {0.f, 0.f};
#pragma unroll
        for (int ec = 0; ec < 2; ++ec) {
            float4 wv[4][4];
            float bo[4];
#pragma unroll
            for (int e4 = 0; e4 < 4; ++e4) {
                bo[e4] = b2sh[(ec * 4 + e4) * 16 + o];
#pragma unroll
                for (int q = 0; q < 4; ++q)
                    wv[e4][q] = *(const float4*)&w2t[o * 132 + (ec * 4 + e4) * 16 + q * 4];
            }
#pragma unroll
            for (int r2 = 0; r2 < 2; ++r2) {
                int r = rb * 2 + r2;
#pragma unroll
                for (int trk = 0; trk < 2; ++trk) {
                    float4 av[4];
#pragma unroll
                    for (int q = 0; q < 4; ++q) av[q] = *(const float4*)&actsh[trk][r][q * 4];
#pragma unroll
                    for (int e4 = 0; e4 < 4; ++e4) {
                        int e = ec * 4 + e4;
                        float t = bo[e4];
                        t = fmaf(av[0].x, wv[e4][0].x, t);
                        t = fmaf(av[0].y, wv[e4][0].y, t);
                        t = fmaf(av[0].z, wv[e4][0].z, t);
                        t = fmaf(av[0].w, wv[e4][0].w, t);
                        t = fmaf(av[1].x, wv[e4][1].x, t);
                        t = fmaf(av[1].y, wv[e4][1].y, t);
                        t = fmaf(av[1].z, wv[e4][1].z, t);
                        t = fmaf(av[1].w, wv[e4][1].w, t);
                        t = fmaf(av[2].x, wv[e4][2].x, t);
                        t = fmaf(av[2].y, wv[e4][2].y, t);
                        t = fmaf(av[2].z, wv[e4][2].z, t);
                        t = fmaf(av[2].w, wv[e4][2].w, t);
                        t = fmaf(av[3].x, wv[e4][3].x, t);
                        t = fmaf(av[3].y, wv[e4][3].y, t);
                        t = fmaf(av[3].z, wv[e4][3].z, t);
                        t = fmaf(av[3].w, wv[e4][3].w, t);
                        zacc[r2] = fmaf(omsh[trk][r][e], t, zacc[r2]);
                    }
                }
            }
        }
#pragma unroll
        for (int r2 = 0; r2 < 2; ++r2) zsh[rb * 2 + r2][o] = zacc[r2];
    }
    __syncthreads();

    // xw: transposed write. thread -> (r = tid&31, gates gi*6..gi*6+5)
    {
        const int r = tid & 31, gi = tid >> 5;
        float4 zv[4];
#pragma unroll
        for (int q = 0; q < 4; ++q) zv[q] = *(const float4*)&zsh[r][q * 4];
        float* __restrict__ xwp = ws + XWT + (size_t)s * 6720 + (size_t)(r0 + r);
#pragma unroll
        for (int gg = 0; gg < 6; ++gg) {
            int g = gi * 6 + gg;
            float a = bihsh[g];
#pragma unroll
            for (int q = 0; q < 4; ++q) {
                float4 wv = *(const float4*)&wihsh[g][q * 4];
                a = fmaf(zv[q].x, wv.x, a);
                a = fmaf(zv[q].y, wv.y, a);
                a = fmaf(zv[q].z, wv.z, a);
                a = fmaf(zv[q].w, wv.w, a);
            }
            xwp[(size_t)g * 140] = a * (g < 32 ? L2E : T2E);
        }
        // zero tail cols 128..131 (read by k4's last chunk, must not be NaN)
        if (r0 == 96 && r < 4) {
#pragma unroll
            for (int gg = 0; gg < 6; ++gg) {
                int g = gi * 6 + gg;
                ws[XWT + (size_t)s * 6720 + (size_t)g * 140 + 128 + r] = 0.f;
            }
        }
    }
}

// ===== K4: main GRU recurrence, 64 blocks x 64 thr, DPP broadcast =====
// No LDS: xw read directly from global (transposed), chunked 4 steps,
// prefetched 2 chunks ahead; swizzle software-pipelined to iteration end.
__global__ __launch_bounds__(64, 1) void k4_rec(
    const float* __restrict__ Whh0, const float* __restrict__ bhh0,
    const float* __restrict__ Wih1, const float* __restrict__ Whh1,
    const float* __restrict__ bih1, const float* __restrict__ bhh1,
    float* __restrict__ ws)
{
    const int s = blockIdx.x;
    const int tid = threadIdx.x;
    const int j = tid & 15;
    const int layer = (tid >> 4) & 1;

    // A = own-layer h (Whh of own layer); B = other-layer h (Wih1, layer1 only)
    const float* __restrict__ WA = layer ? Whh1 : Whh0;
    const float mhi = layer ? 1.f : 0.f;
    const float m0f = layer ? 0.f : 1.f;
    f2 wa2r[8], wa2z[8], wa2c[8], wb2r[8], wb2z[8], wb2c[8];
#pragma unroll
    for (int m = 0; m < 8; ++m) {
        int k0 = (j - 2 * m) & 15, k1i = (j - 2 * m - 1) & 15;
        wa2r[m].x = L2E * WA[j * 16 + k0];        wa2r[m].y = L2E * WA[j * 16 + k1i];
        wa2z[m].x = L2E * WA[(16 + j) * 16 + k0]; wa2z[m].y = L2E * WA[(16 + j) * 16 + k1i];
        wa2c[m].x = T2E * WA[(32 + j) * 16 + k0]; wa2c[m].y = T2E * WA[(32 + j) * 16 + k1i];
        wb2r[m].x = mhi * L2E * Wih1[j * 16 + k0];        wb2r[m].y = mhi * L2E * Wih1[j * 16 + k1i];
        wb2z[m].x = mhi * L2E * Wih1[(16 + j) * 16 + k0]; wb2z[m].y = mhi * L2E * Wih1[(16 + j) * 16 + k1i];
        wb2c[m].x = mhi * T2E * Wih1[(32 + j) * 16 + k0]; wb2c[m].y = mhi * T2E * Wih1[(32 + j) * 16 + k1i];
    }
    const float base_r  = L2E * (layer ? (bih1[j] + bhh1[j])           : bhh0[j]);
    const float base_z  = L2E * (layer ? (bih1[16 + j] + bhh1[16 + j]) : bhh0[16 + j]);
    const float base_in = T2E * (layer ? bih1[32 + j]                  : 0.f);
    const float base_dn = T2E * (layer ? bhh1[32 + j]                  : bhh0[32 + j]);

    const float* __restrict__ xwb = ws + XWT + (size_t)s * 6720;
    const float* __restrict__ r0p = xwb + (size_t)j * 140;
    const float* __restrict__ r1p = xwb + (size_t)(16 + j) * 140;
    const float* __restrict__ r2p = xwb + (size_t)(32 + j) * 140;

    float4 d0 = *(const float4*)(r0p);
    float4 d1 = *(const float4*)(r1p);
    float4 d2 = *(const float4*)(r2p);
    float4 n0v = *(const float4*)(r0p + 4);
    float4 n1v = *(const float4*)(r1p + 4);
    float4 n2v = *(const float4*)(r2p + 4);

    float hown = 0.f, b0 = 0.f;
#pragma unroll 1
    for (int tc = 0; tc < 33; ++tc) {
        float4 e0 = d0, e1 = d1, e2 = d2;
        d0 = n0v; d1 = n1v; d2 = n2v;
        int nc = tc + 2; if (nc > 32) nc = 32;
        n0v = *(const float4*)(r0p + nc * 4);
        n1v = *(const float4*)(r1p + nc * 4);
        n2v = *(const float4*)(r2p + nc * 4);
#pragma unroll
        for (int tt = 0; tt < 4; ++tt) {
            const int t = tc * 4 + tt;
            float p0 = tt == 0 ? e0.x : tt == 1 ? e0.y : tt == 2 ? e0.z : e0.w;
            float p1 = tt == 0 ? e1.x : tt == 1 ? e1.y : tt == 2 ? e1.z : e1.w;
            float p2 = tt == 0 ? e2.x : tt == 1 ? e2.y : tt == 2 ? e2.z : e2.w;
            f2 A2[8], B2[8];
            A2[0].x = hown;            A2[0].y = rorf<1>(hown);
            A2[1].x = rorf<2>(hown);   A2[1].y = rorf<3>(hown);
            A2[2].x = rorf<4>(hown);   A2[2].y = rorf<5>(hown);
            A2[3].x = rorf<6>(hown);   A2[3].y = rorf<7>(hown);
            A2[4].x = rorf<8>(hown);   A2[4].y = rorf<9>(hown);
            A2[5].x = rorf<10>(hown);  A2[5].y = rorf<11>(hown);
            A2[6].x = rorf<12>(hown);  A2[6].y = rorf<13>(hown);
            A2[7].x = rorf<14>(hown);  A2[7].y = rorf<15>(hown);
            B2[0].x = b0;              B2[0].y = rorf<1>(b0);
            B2[1].x = rorf<2>(b0);     B2[1].y = rorf<3>(b0);
            B2[2].x = rorf<4>(b0);     B2[2].y = rorf<5>(b0);
            B2[3].x = rorf<6>(b0);     B2[3].y = rorf<7>(b0);
            B2[4].x = rorf<8>(b0);     B2[4].y = rorf<9>(b0);
            B2[5].x = rorf<10>(b0);    B2[5].y = rorf<11>(b0);
            B2[6].x = rorf<12>(b0);    B2[6].y = rorf<13>(b0);
            B2[7].x = rorf<14>(b0);    B2[7].y = rorf<15>(b0);

            f2 sra = wa2r[0] * A2[0], srb = wb2r[0] * B2[0];
            f2 sza = wa2z[0] * A2[0], szb = wb2z[0] * B2[0];
            f2 sca = wa2c[0] * A2[0], scb = wb2c[0] * B2[0];
#pragma unroll
            for (int m = 1; m < 8; ++m) {
                sra += wa2r[m] * A2[m];  srb += wb2r[m] * B2[m];
                sza += wa2z[m] * A2[m];  szb += wb2z[m] * B2[m];
                sca += wa2c[m] * A2[m];  scb += wb2c[m] * B2[m];
            }
            f2 sr = sra + srb, sz = sza + szb;
            float ar = fmaf(m0f, p0, base_r) + sr.x + sr.y;
            float az = fmaf(m0f, p1, base_z) + sz.x + sz.y;
            float acA = sca.x + sca.y;
            float acB = scb.x + scb.y;
            float r = fsig2(ar);
            float z = fsig2(az);
            float in_ = layer ? (base_in + acB) : p2;
            float dn  = base_dn + acA;
            float n = ftanh2(fmaf(r, dn, in_));
            float hnew = fmaf(z, hown - n, n);
            bool act = layer ? (t >= 1 && t < 129) : (t < 128);
            hown = act ? hnew : hown;
            b0 = swzx16(hown);   // pipelined: consumed next iteration
        }
    }
    if (tid >= 16 && tid < 32) ws[ZLAST + (size_t)s * 16 + j] = hown;
}

// ===== K34 fallback: fused phase A + phase B (used if ws too small) =====
__global__ __launch_bounds__(256, 1) void k34_fused(
    const float* __restrict__ ae_w2, const float* __restrict__ ae_b2,
    const float* __restrict__ ae_g, const float* __restrict__ ae_bt,
    const float* __restrict__ mWih0, const float* __restrict__ mbih0,
    const float* __restrict__ Whh0, const float* __restrict__ bhh0,
    const float* __restrict__ Wih1, const float* __restrict__ Whh1,
    const float* __restrict__ bih1, const float* __restrict__ bhh1,
    float* __restrict__ ws)
{
    const int s = blockIdx.x;
    const int tid = threadIdx.x;

    __shared__ float stat[4][16];
    __shared__ float omsh[2][128][8];
    __shared__ __align__(16) float w2t[16 * 132];
    __shared__ float b2sh[128];
    __shared__ __align__(16) float actsh[2][128][16];
    __shared__ __align__(16) float zsh[128][20];
    __shared__ __align__(16) float wihsh[48][20];
    __shared__ float bihsh[48];
    __shared__ float xwsh[128 * 48];

    if (tid < 32) {
        int trk = tid >> 4, h = tid & 15;
        float sm = ws[ACC + trk * 32 + h], s2 = ws[ACC + trk * 32 + 16 + h];
        float m = sm * (1.f / 8192.f);
        float v = fmaxf(s2 * (1.f / 8192.f) - m * m, 0.f);
        stat[trk * 2][h] = m;
        stat[trk * 2 + 1][h] = rsqrtf(v + 1e-5f);
    }
    for (int i = tid; i < 2048; i += 256) {
        int e = i >> 8, h = (i >> 4) & 15, o = i & 15;
        w2t[o * 132 + e * 16 + h] = ae_w2[i];
    }
    for (int i = tid; i < 128; i += 256) b2sh[i] = ae_b2[i];
    for (int i = tid; i < 768; i += 256) wihsh[i >> 4][i & 15] = mWih0[i];
    if (tid < 48) bihsh[tid] = mbih0[tid];
    for (int i = tid; i < 2048; i += 256) {
        int trk = i >> 10, r = (i >> 3) & 127, e = i & 7;
        omsh[trk][r][e] = ws[(trk ? RO : LO) + ((size_t)s * 128 + r) * 8 + e];
    }
    __syncthreads();

    for (int i = tid; i < 4096; i += 256) {
        int trk = i >> 11, r = (i >> 4) & 127, h = i & 15;
        float v = ws[HBUF + (size_t)trk * 131072 + ((size_t)s * 128 + r) * 16 + h];
        float a = ae_g[h] * (v - stat[trk * 2][h]) * stat[trk * 2 + 1][h] + ae_bt[h];
        actsh[trk][r][h] = a > 0.f ? a : expm1f(a);
    }
    __syncthreads();

    {
        const int o = tid & 15, rb = tid >> 4;
        float zacc[8];
#pragma unroll
        for (int r8 = 0; r8 < 8; ++r8) zacc[r8] = 0.f;
#pragma unroll
        for (int ec = 0; ec < 2; ++ec) {
            float4 wv[4][4];
#pragma unroll
            for (int e4 = 0; e4 < 4; ++e4)
#pragma unroll
                for (int q = 0; q < 4; ++q)
                    wv[e4][q] = *(const float4*)&w2t[o * 132 + (ec * 4 + e4) * 16 + q * 4];
#pragma unroll
            for (int r8 = 0; r8 < 8; ++r8) {
                int r = rb * 8 + r8;
#pragma unroll
                for (int trk = 0; trk < 2; ++trk) {
                    float4 av[4];
#pragma unroll
                    for (int q = 0; q < 4; ++q) av[q] = *(const float4*)&actsh[trk][r][q * 4];
#pragma unroll
                    for (int e4 = 0; e4 < 4; ++e4) {
                        int e = ec * 4 + e4;
                        float t = b2sh[e * 16 + o];
                        t = fmaf(av[0].x, wv[e4][0].x, t);
                        t = fmaf(av[0].y, wv[e4][0].y, t);
                        t = fmaf(av[0].z, wv[e4][0].z, t);
                        t = fmaf(av[0].w, wv[e4][0].w, t);
                        t = fmaf(av[1].x, wv[e4][1].x, t);
                        t = fmaf(av[1].y, wv[e4][1].y, t);
                        t = fmaf(av[1].z, wv[e4][1].z, t);
                        t = fmaf(av[1].w, wv[e4][1].w, t);
                        t = fmaf(av[2].x, wv[e4][2].x, t);
                        t = fmaf(av[2].y, wv[e4][2].y, t);
                        t = fmaf(av[2].z, wv[e4][2].z, t);
                        t = fmaf(av[2].w, wv[e4][2].w, t);
                        t = fmaf(av[3].x, wv[e4][3].x, t);
                        t = fmaf(av[3].y, wv[e4][3].y, t);
                        t = fmaf(av[3].z, wv[e4][3].z, t);
                        t = fmaf(av[3].w, wv[e4][3].w, t);
                        zacc[r8] = fmaf(omsh[trk][r][e], t, zacc[r8]);
                    }
                }
            }
        }
#pragma unroll
        for (int r8 = 0; r8 < 8; ++r8) zsh[rb * 8 + r8][o] = zacc[r8];
    }
    __syncthreads();

    {
        const int r = tid >> 1, gh = (tid & 1) * 24;
        float4 zv[4];
#pragma unroll
        for (int q = 0; q < 4; ++q) zv[q] = *(const float4*)&zsh[r][q * 4];
#pragma unroll
        for (int gg = 0; gg < 24; ++gg) {
            int g = gh + gg;
            float a = bihsh[g];
#pragma unroll
            for (int q = 0; q < 4; ++q) {
                float4 wv = *(const float4*)&wihsh[g][q * 4];
                a = fmaf(zv[q].x, wv.x, a);
                a = fmaf(zv[q].y, wv.y, a);
                a = fmaf(zv[q].z, wv.z, a);
                a = fmaf(zv[q].w, wv.w, a);
            }
            xwsh[r * 48 + g] = a * (g < 32 ? L2E : T2E);
        }
    }
    __syncthreads();

    if (tid >= 64) return;

    const int j = tid & 15;
    const int layer = (tid >> 4) & 1;

    const float* __restrict__ Wlo = layer ? Wih1 : Whh0;
    const float mhi = layer ? 1.f : 0.f;
    const float m0f = layer ? 0.f : 1.f;
    f2 wr2[16], wz2[16], wc2[16];
#pragma unroll
    for (int m = 0; m < 8; ++m) {
        wr2[m].x = L2E * Wlo[j * 16 + 2 * m];
        wr2[m].y = L2E * Wlo[j * 16 + 2 * m + 1];
        wz2[m].x = L2E * Wlo[(16 + j) * 16 + 2 * m];
        wz2[m].y = L2E * Wlo[(16 + j) * 16 + 2 * m + 1];
        wc2[m].x = T2E * Wlo[(32 + j) * 16 + 2 * m];
        wc2[m].y = T2E * Wlo[(32 + j) * 16 + 2 * m + 1];
        wr2[8 + m].x = mhi * L2E * Whh1[j * 16 + 2 * m];
        wr2[8 + m].y = mhi * L2E * Whh1[j * 16 + 2 * m + 1];
        wz2[8 + m].x = mhi * L2E * Whh1[(16 + j) * 16 + 2 * m];
        wz2[8 + m].y = mhi * L2E * Whh1[(16 + j) * 16 + 2 * m + 1];
        wc2[8 + m].x = mhi * T2E * Whh1[(32 + j) * 16 + 2 * m];
        wc2[8 + m].y = mhi * T2E * Whh1[(32 + j) * 16 + 2 * m + 1];
    }
    const float base_r  = L2E * (layer ? (bih1[j] + bhh1[j])           : bhh0[j]);
    const float base_z  = L2E * (layer ? (bih1[16 + j] + bhh1[16 + j]) : bhh0[16 + j]);
    const float base_in = T2E * (layer ? bih1[32 + j]                  : 0.f);
    const float base_dn = T2E * (layer ? bhh1[32 + j]                  : bhh0[32 + j]);

    float hown = 0.f;
    float p0 = xwsh[j], p1 = xwsh[16 + j], p2 = xwsh[32 + j];
#pragma unroll 1
    for (int t = 0; t <= 128; ++t) {
        int tn = (t < 127 ? t + 1 : 127) * 48;
        float q0 = xwsh[tn + j], q1 = xwsh[tn + 16 + j], q2 = xwsh[tn + 32 + j];
        f2 vb2[16];
#pragma unroll
        for (int m = 0; m < 16; ++m) {
            vb2[m].x = readlanef(hown, 2 * m);
            vb2[m].y = readlanef(hown, 2 * m + 1);
        }
        f2 srE = wr2[0] * vb2[0], srO = wr2[1] * vb2[1];
        f2 szE = wz2[0] * vb2[0], szO = wz2[1] * vb2[1];
#pragma unroll
        for (int m = 2; m < 16; m += 2) {
            srE += wr2[m] * vb2[m];     srO += wr2[m + 1] * vb2[m + 1];
            szE += wz2[m] * vb2[m];     szO += wz2[m + 1] * vb2[m + 1];
        }
        f2 scA = wc2[0] * vb2[0], scB = wc2[1] * vb2[1];
        f2 scC = wc2[8] * vb2[8], scD = wc2[9] * vb2[9];
#pragma unroll
        for (int m = 2; m < 8; m += 2) {
            scA += wc2[m] * vb2[m];         scB += wc2[m + 1] * vb2[m + 1];
            scC += wc2[8 + m] * vb2[8 + m]; scD += wc2[9 + m] * vb2[9 + m];
        }
        f2 sr = srE + srO, sz = szE + szO;
        f2 scL = scA + scB, scH = scC + scD;
        float ar = fmaf(m0f, p0, base_r) + sr.x + sr.y;
        float az = fmaf(m0f, p1, base_z) + sz.x + sz.y;
        float ac_lo = scL.x + scL.y;
        float ac_hi = scH.x + scH.y;
        float r = fsig2(ar);
        float z = fsig2(az);
        float in_ = layer ? (base_in + ac_lo) : p2;
        float dn  = base_dn + (layer ? ac_hi : ac_lo);
        float n = ftanh2(fmaf(r, dn, in_));
        float hnew = fmaf(z, hown - n, n);
        bool act = layer ? (t >= 1) : (t < 128);
        hown = act ? hnew : hown;
        p0 = q0; p1 = q1; p2 = q2;
    }
    if (tid >= 16 && tid < 32) ws[ZLAST + (size_t)s * 16 + j] = hown;
}

// ===== K5: decoder MLP fused (layer1+BN redundant per block, layer2 slice) =====
__global__ __launch_bounds__(256) void k5_dec(
    const float* __restrict__ Remote,
    const float* __restrict__ md_w1, const float* __restrict__ md_b1,
    const float* __restrict__ md_g, const float* __restrict__ md_bt,
    const float* __restrict__ md_w2, const float* __restrict__ md_b2,
    const float* __restrict__ ws, float* __restrict__ out)
{
    const int o0 = blockIdx.x * 8;
    const int tid = threadIdx.x;
    __shared__ float xsh[64][17];
    __shared__ float omsh[64][8];
    __shared__ float w1sh[2176];
    __shared__ float b1sh[128];
    __shared__ float hsh[64][17];
    __shared__ float ssum[16], ss2[16], mstat[2][16];
    __shared__ float ash[64][17];
    __shared__ float w2sh[8][16][8];
    __shared__ float b2sh[8][8];

    for (int i = tid; i < 1024; i += 256) xsh[i >> 4][i & 15] = ws[ZLAST + i];
    if (tid < 64) xsh[tid][16] = Remote[((size_t)tid * 128 + 127) * 132 + 131];
    for (int i = tid; i < 512; i += 256)
        omsh[i >> 3][i & 7] = ws[RO + ((size_t)(i >> 3) * 128 + 127) * 8 + (i & 7)];
    for (int i = tid; i < 2176; i += 256) w1sh[i] = md_w1[i];
    for (int i = tid; i < 128; i += 256) b1sh[i] = md_b1[i];
    for (int i = tid; i < 1024; i += 256) {
        int e = i >> 7, h = (i >> 3) & 15, oo = i & 7;
        w2sh[e][h][oo] = md_w2[((size_t)e * 16 + h) * 128 + o0 + oo];
    }
    if (tid < 64) b2sh[tid >> 3][tid & 7] = md_b2[(size_t)(tid >> 3) * 128 + o0 + (tid & 7)];
    if (tid < 16) { ssum[tid] = 0.f; ss2[tid] = 0.f; }
    __syncthreads();

    for (int i = tid; i < 1024; i += 256) {
        int b = i >> 4, h = i & 15;
        float accv = 0.f;
#pragma unroll
        for (int e = 0; e < 8; ++e) {
            float t = b1sh[e * 16 + h];
            const float* w = &w1sh[e * 272 + h];
#pragma unroll
            for (int i2 = 0; i2 < 17; ++i2) t = fmaf(xsh[b][i2], w[i2 * 16], t);
            accv = fmaf(omsh[b][e], t, accv);
        }
        hsh[b][h] = accv;
        atomicAdd(&ssum[h], accv);
        atomicAdd(&ss2[h], accv * accv);
    }
    __syncthreads();
    if (tid < 16) {
        float m = ssum[tid] * (1.f / 64.f);
        float v = fmaxf(ss2[tid] * (1.f / 64.f) - m * m, 0.f);
        mstat[0][tid] = m;
        mstat[1][tid] = rsqrtf(v + 1e-5f);
    }
    __syncthreads();
    for (int i = tid; i < 1024; i += 256) {
        int b = i >> 4, h = i & 15;
        float a = md_g[h] * (hsh[b][h] - mstat[0][h]) * mstat[1][h] + md_bt[h];
        ash[b][h] = a > 0.f ? a : expm1f(a);
    }
    __syncthreads();

    for (int i = tid; i < 512; i += 256) {
        int b = i >> 3, oo = i & 7;
        float accv = 0.f;
#pragma unroll
        for (int e = 0; e < 8; ++e) {
            float t = b2sh[e][oo];
#pragma unroll
            for (int h = 0; h < 16; ++h) t = fmaf(ash[b][h], w2sh[e][h][oo], t);
            accv = fmaf(omsh[b][e], t, accv);
        }
        out[(size_t)b * 128 + o0 + oo] = accv;
    }
}

extern "C" void kernel_launch(void* const* d_in, const int* in_sizes, int n_in,
                              void* d_out, int out_size, void* d_ws, size_t ws_size,
                              hipStream_t stream) {
    const float* Local  = (const float*)d_in[0];
    const float* Remote = (const float*)d_in[1];
    const float* gWih0  = (const float*)d_in[2];
    const float* gWhh0  = (const float*)d_in[3];
    const float* gbih0  = (const float*)d_in[4];
    const float* gbhh0  = (const float*)d_in[5];
    const float* gWih1  = (const float*)d_in[6];
    const float* gWhh1  = (const float*)d_in[7];
    const float* gbih1  = (const float*)d_in[8];
    const float* gbhh1  = (const float*)d_in[9];
    const float* mWih0  = (const float*)d_in[10];
    const float* mWhh0  = (const float*)d_in[11];
    const float* mbih0  = (const float*)d_in[12];
    const float* mbhh0  = (const float*)d_in[13];
    const float* mWih1  = (const float*)d_in[14];
    const float* mWhh1  = (const float*)d_in[15];
    const float* mbih1  = (const float*)d_in[16];
    const float* mbhh1  = (const float*)d_in[17];
    const float* ae_w1  = (const float*)d_in[18];
    const float* ae_b1  = (const float*)d_in[19];
    const float* ae_w2  = (const float*)d_in[20];
    const float* ae_b2  = (const float*)d_in[21];
    const float* ae_g   = (const float*)d_in[22];
    const float* ae_bt  = (const float*)d_in[23];
    const float* md_w1  = (const float*)d_in[24];
    const float* md_b1  = (const float*)d_in[25];
    const float* md_w2  = (const float*)d_in[26];
    const float* md_b2  = (const float*)d_in[27];
    const float* md_g   = (const float*)d_in[28];
    const float* md_bt  = (const float*)d_in[29];
    float* ws  = (float*)d_ws;
    float* out = (float*)d_out;

    k1_gate<<<128, 64, 0, stream>>>(Local, Remote, gWih0, gWhh0, gbih0, gbhh0,
                                    gWih1, gWhh1, gbih1, gbhh1, ws);
    k2_expert1<<<256, 256, 0, stream>>>(Local, Remote, ae_w1, ae_b1, ws);
    if (ws_size >= WS_NEED * sizeof(float)) {
        k3_phaseA<<<256, 256, 0, stream>>>(ae_w2, ae_b2, ae_g, ae_bt, mWih0, mbih0, ws);
        k4_rec<<<64, 64, 0, stream>>>(mWhh0, mbhh0, mWih1, mWhh1, mbih1, mbhh1, ws);
    } else {
        k34_fused<<<64, 256, 0, stream>>>(ae_w2, ae_b2, ae_g, ae_bt, mWih0, mbih0,
                                          mWhh0, mbhh0, mWih1, mWhh1, mbih1, mbhh1, ws);
    }
    k5_dec<<<16, 256, 0, stream>>>(Remote, md_w1, md_b1, md_g, md_bt,
                                   md_w2, md_b2, ws, out);
}